// Round 1
// 160.309 us; speedup vs baseline: 1.0391x; 1.0391x over previous
//
#include <hip/hip_runtime.h>
#include <cstdint>
#include <cstddef>

#define NI   256
#define QKC  32
#define BS   4
#define NPIX 4096   // 64*64
#define LOG2E 1.4426950408889634f

typedef __bf16 bf16x8 __attribute__((ext_vector_type(8)));
typedef __bf16 bf16x4 __attribute__((ext_vector_type(4)));
typedef float  f32x16 __attribute__((ext_vector_type(16)));

__device__ inline f32x16 zero16() {
    f32x16 z;
    #pragma unroll
    for (int i = 0; i < 16; ++i) z[i] = 0.f;
    return z;
}

// ---------------- Kernel 0: W -> fragment-packed bf16 ----------------
// wpack[otl(10)][kk(16)][h(2)][l31(32)][8]: A-frag-ready, 16B per (lane,kk).
__global__ __launch_bounds__(256) void wconv_pack(
    const float* __restrict__ wq, const float* __restrict__ wk,
    const float* __restrict__ wv, __bf16* __restrict__ wpk)
{
    int f = blockIdx.x * 256 + threadIdx.x;          // 0..10239
    int otl = f >> 10, rem = f & 1023;
    int kk = rem >> 6, h = (rem >> 5) & 1, l31 = rem & 31;
    int och = otl * 32 + l31, c0 = kk * 16 + 8 * h;
    const float* src = och < 32 ? wq + och * NI + c0
                     : och < 64 ? wk + (och - 32) * NI + c0
                                : wv + (och - 64) * NI + c0;
    float4 x0 = *(const float4*)src;
    float4 x1 = *(const float4*)(src + 4);
    __align__(16) __bf16 o8[8] = {
        (__bf16)x0.x, (__bf16)x0.y, (__bf16)x0.z, (__bf16)x0.w,
        (__bf16)x1.x, (__bf16)x1.y, (__bf16)x1.z, (__bf16)x1.w};
    *(uint4*)(wpk + (size_t)f * 8) = *(const uint4*)o8;
}

// ---------------- Kernel 1: QKV -> packed fragment outputs ----------------
__global__ __launch_bounds__(256) void qkv_mfma(
    const float* __restrict__ x, const __bf16* __restrict__ wpk,
    const float* __restrict__ bq, const float* __restrict__ bk,
    const float* __restrict__ bv,
    __bf16* __restrict__ qpk, __bf16* __restrict__ kpk, __bf16* __restrict__ vpk)
{
    __shared__ __align__(16) __bf16 xT[32][264];   // also reused as vT
    __shared__ float bls[320];

    const int t = threadIdx.x, w = t >> 6, lane = t & 63;
    const int l31 = lane & 31, h = lane >> 5;
    const int b = blockIdx.y, n0 = blockIdx.x * 32, kt = blockIdx.x;

    for (int i = t; i < 320; i += 256)
        bls[i] = i < 32 ? bq[i] : i < 64 ? bk[i - 32] : bv[i - 64];

    {   // stage x transposed (32 n x 256 c)
        int n4 = (t & 7) * 4, cb = (t >> 3) * 8;
        float4 xv[8];
        #pragma unroll
        for (int j = 0; j < 8; ++j)
            xv[j] = *(const float4*)(x + ((size_t)(b * NI) + cb + j) * NPIX + n0 + n4);
        #pragma unroll
        for (int i = 0; i < 4; ++i) {
            __align__(16) __bf16 r8[8];
            #pragma unroll
            for (int j = 0; j < 8; ++j) r8[j] = (__bf16)((&xv[j].x)[i]);
            *(uint4*)&xT[n4 + i][cb] = *(const uint4*)r8;
        }
    }
    __syncthreads();

    f32x16 acc[3] = {zero16(), zero16(), zero16()};
    #pragma unroll 4
    for (int kk = 0; kk < 16; ++kk) {
        bf16x8 xf = *(const bf16x8*)&xT[l31][kk * 16 + 8 * h];
        #pragma unroll
        for (int jj = 0; jj < 3; ++jj) {
            int otl = w + 4 * jj;
            if (otl < 10) {
                bf16x8 wf = *(const bf16x8*)(wpk + (size_t)((otl * 16 + kk) * 64 + 32 * h + l31) * 8);
                acc[jj] = __builtin_amdgcn_mfma_f32_32x32x16_bf16(wf, xf, acc[jj], 0, 0, 0);
            }
        }
    }
    __syncthreads();   // xT reads done; reuse as vT

    __bf16 (*vT)[264] = xT;
    // v tiles -> vT[key l31][c], b64 quad writes
    #pragma unroll
    for (int jj = 0; jj < 3; ++jj) {
        int otl = w + 4 * jj;
        if (otl >= 2 && otl < 10) {
            #pragma unroll
            for (int qd = 0; qd < 4; ++qd) {
                int c0v = (otl - 2) * 32 + 8 * qd + 4 * h;
                __align__(8) __bf16 q4[4];
                #pragma unroll
                for (int i = 0; i < 4; ++i)
                    q4[i] = (__bf16)(acc[jj][4 * qd + i] + bls[64 + c0v + i]);
                *(uint2*)&vT[l31][c0v] = *(const uint2*)q4;
            }
        }
    }
    // q/k packs straight from C-regs (coalesced b128 global stores)
    #pragma unroll
    for (int jj = 0; jj < 3; ++jj) {
        int otl = w + 4 * jj;
        if (otl == 0) {        // q: scale by log2e, hi/lo split
            #pragma unroll
            for (int kc = 0; kc < 2; ++kc) {
                __align__(16) __bf16 hi8[8], lo8[8];
                #pragma unroll
                for (int j = 0; j < 8; ++j) {
                    int r = 8 * kc + j;
                    int och = (r & 3) + 8 * (r >> 2) + 4 * h;
                    float val = (acc[jj][r] + bls[och]) * LOG2E;
                    __bf16 hh = (__bf16)val;
                    hi8[j] = hh;
                    lo8[j] = (__bf16)(val - (float)hh);
                }
                size_t base = ((((size_t)(b * 128 + kt) * 2 + 0) * 2 + kc) * 2 + h) * 32 + l31;
                *(uint4*)(qpk + base * 8) = *(const uint4*)hi8;
                size_t basel = ((((size_t)(b * 128 + kt) * 2 + 1) * 2 + kc) * 2 + h) * 32 + l31;
                *(uint4*)(qpk + basel * 8) = *(const uint4*)lo8;
            }
        } else if (otl == 1) { // k
            #pragma unroll
            for (int kc = 0; kc < 2; ++kc) {
                __align__(16) __bf16 k8[8];
                #pragma unroll
                for (int j = 0; j < 8; ++j) {
                    int r = 8 * kc + j;
                    int och = (r & 3) + 8 * (r >> 2) + 4 * h;
                    k8[j] = (__bf16)(acc[jj][r] + bls[32 + och]);
                }
                size_t base = (((size_t)(b * 128 + kt) * 2 + kc) * 2 + h) * 32 + l31;
                *(uint4*)(kpk + base * 8) = *(const uint4*)k8;
            }
        }
    }
    __syncthreads();   // vT complete

    // vpack emit: thread t owns c'=t; frag (kc,hh) = keys 16kc+8hh+j
    #pragma unroll
    for (int kc = 0; kc < 2; ++kc)
        #pragma unroll
        for (int hh = 0; hh < 2; ++hh) {
            __align__(16) __bf16 f8[8];
            #pragma unroll
            for (int j = 0; j < 8; ++j) f8[j] = vT[16 * kc + 8 * hh + j][t];
            size_t base = (((size_t)(b * 128 + kt) * 2 + kc) * 2 + hh) * 256 + t;
            *(uint4*)(vpk + base * 8) = *(const uint4*)f8;
        }
}

// ---------------- Kernel 2: attention, KSPLIT-way key split ----------------
// grid (64 n-tiles, KSPLIT key-groups, 4 b). Occupancy lever: KSPLIT=4 gives
// 1024 blocks = 4 blocks/CU = 4 waves/SIMD (was 2), hiding the per-mt
// barrier + exp2 VALU under more concurrent MFMA streams.
template <int KSPLIT>
__global__ __launch_bounds__(256) void attn_mfma(
    const __bf16* __restrict__ qpk, const __bf16* __restrict__ kpk,
    const __bf16* __restrict__ vpk,
    __bf16* __restrict__ Opart, float* __restrict__ dpart)
{
    constexpr int MT = 64 / KSPLIT;          // key double-tiles per block
    __shared__ __align__(16) __bf16 pt_s[2][64][72];   // 18432 B
    __shared__ float dwave[4][32];

    const int t = threadIdx.x;
    const int b = blockIdx.z, ksp = blockIdx.y;
    const int n0 = blockIdx.x * 64;
    const int w = t >> 6, lane = t & 63, l31 = lane & 31, h = lane >> 5;
    const int sr = w & 1, sc = w >> 1;
    const int kt0 = ksp * (128 / KSPLIT);

    // Q fragments (hi/lo x kc)
    const int qt = 2 * blockIdx.x + sr;
    bf16x8 qf[2][2];
    #pragma unroll
    for (int hl = 0; hl < 2; ++hl)
        #pragma unroll
        for (int kc = 0; kc < 2; ++kc)
            qf[hl][kc] = *(const bf16x8*)(qpk +
                (((((size_t)(b * 128 + qt) * 2 + hl) * 2 + kc) * 2 + h) * 32 + l31) * 8);

    auto kload = [&](int ktile, int kc) {
        return *(const bf16x8*)(kpk +
            ((((size_t)(b * 128 + ktile) * 2 + kc) * 2 + h) * 32 + l31) * 8);
    };

    f32x16 a00 = zero16(), a01 = zero16(), a10 = zero16(), a11 = zero16();
    float dacc = 0.f;

    auto sblock = [&](bf16x8 kh0, bf16x8 kh1, int buf) {
        f32x16 s = zero16();
        __builtin_amdgcn_s_setprio(1);
        s = __builtin_amdgcn_mfma_f32_32x32x16_bf16(kh0, qf[0][0], s, 0, 0, 0);
        s = __builtin_amdgcn_mfma_f32_32x32x16_bf16(kh1, qf[0][1], s, 0, 0, 0);
        s = __builtin_amdgcn_mfma_f32_32x32x16_bf16(kh0, qf[1][0], s, 0, 0, 0);
        s = __builtin_amdgcn_mfma_f32_32x32x16_bf16(kh1, qf[1][1], s, 0, 0, 0);
        __builtin_amdgcn_s_setprio(0);
        #pragma unroll
        for (int qd = 0; qd < 4; ++qd) {
            __align__(8) __bf16 e4[4];
            #pragma unroll
            for (int i = 0; i < 4; ++i) {
                float e = __builtin_amdgcn_exp2f(s[4 * qd + i]);
                dacc += e;
                e4[i] = (__bf16)e;
            }
            *(uint2*)&pt_s[buf][32 * sr + l31][32 * sc + 8 * qd + 4 * h] = *(const uint2*)e4;
        }
    };

    // prologue: S(0) -> pt[0], prefetch K(1)
    bf16x8 kh0 = kload(kt0 + sc, 0), kh1 = kload(kt0 + sc, 1);
    sblock(kh0, kh1, 0);
    kh0 = kload(kt0 + 2 + sc, 0); kh1 = kload(kt0 + 2 + sc, 1);
    __syncthreads();

    for (int mt = 0; mt < MT; ++mt) {
        const int cur = mt & 1;

        bf16x8 vf[2][2][2];
        #pragma unroll
        for (int i = 0; i < 2; ++i)
            #pragma unroll
            for (int kc = 0; kc < 2; ++kc)
                #pragma unroll
                for (int ctl = 0; ctl < 2; ++ctl)
                    vf[i][kc][ctl] = *(const bf16x8*)(vpk +
                        ((((size_t)(b * 128 + kt0 + 2 * mt + i) * 2 + kc) * 2 + h) * 256
                         + 64 * w + 32 * ctl + l31) * 8);

        if (mt < MT - 1) {
            bf16x8 k0 = kh0, k1 = kh1;
            if (mt < MT - 2) {
                kh0 = kload(kt0 + 2 * (mt + 2) + sc, 0);
                kh1 = kload(kt0 + 2 * (mt + 2) + sc, 1);
            }
            sblock(k0, k1, 1 - cur);
        }

        __builtin_amdgcn_s_setprio(1);
        #pragma unroll
        for (int i = 0; i < 2; ++i)
            #pragma unroll
            for (int kc = 0; kc < 2; ++kc) {
                int col = 32 * i + 16 * kc + 8 * h;
                bf16x8 pa0 = *(const bf16x8*)&pt_s[cur][l31][col];
                bf16x8 pa1 = *(const bf16x8*)&pt_s[cur][32 + l31][col];
                a00 = __builtin_amdgcn_mfma_f32_32x32x16_bf16(pa0, vf[i][kc][0], a00, 0, 0, 0);
                a10 = __builtin_amdgcn_mfma_f32_32x32x16_bf16(pa1, vf[i][kc][0], a10, 0, 0, 0);
                a01 = __builtin_amdgcn_mfma_f32_32x32x16_bf16(pa0, vf[i][kc][1], a01, 0, 0, 0);
                a11 = __builtin_amdgcn_mfma_f32_32x32x16_bf16(pa1, vf[i][kc][1], a11, 0, 0, 0);
            }
        __builtin_amdgcn_s_setprio(0);
        __syncthreads();
    }

    // ---- epilogue ----
    float dtot = dacc + __shfl_xor(dacc, 32);   // fold h halves (same n)
    if (lane < 32) dwave[w][l31] = dtot;
    __syncthreads();
    if (w < 2 && lane < 32) {
        size_t dbase = ((size_t)(ksp * BS + b)) * NPIX + n0 + 32 * w;
        dpart[dbase + l31] = dwave[w][l31] + dwave[w + 2][l31];
    }

    size_t obase = (((size_t)(ksp * BS + b)) * NI + 64 * w + l31) * NPIX + n0;
    #pragma unroll
    for (int rq = 0; rq < 4; ++rq) {
        int nn = 8 * rq + 4 * h;
        __align__(8) __bf16 t00[4], t10[4], t01[4], t11[4];
        #pragma unroll
        for (int i = 0; i < 4; ++i) {
            t00[i] = (__bf16)a00[4 * rq + i];
            t10[i] = (__bf16)a10[4 * rq + i];
            t01[i] = (__bf16)a01[4 * rq + i];
            t11[i] = (__bf16)a11[4 * rq + i];
        }
        *(uint2*)(Opart + obase + nn)                          = *(const uint2*)t00;
        *(uint2*)(Opart + obase + 32 + nn)                     = *(const uint2*)t10;
        *(uint2*)(Opart + obase + (size_t)32 * NPIX + nn)      = *(const uint2*)t01;
        *(uint2*)(Opart + obase + (size_t)32 * NPIX + 32 + nn) = *(const uint2*)t11;
    }
}

// ---------------- Kernel 3: combine over KSPLIT partials ----------------
template <int KSPLIT>
__global__ __launch_bounds__(256) void combine(
    const float* __restrict__ x, const float* __restrict__ gamma,
    const __bf16* __restrict__ Opart, const float* __restrict__ dpart,
    float* __restrict__ out)
{
    int idx = (blockIdx.x * 256 + threadIdx.x) * 4;
    int n = idx & (NPIX - 1);
    int c = (idx >> 12) & (NI - 1);
    int b = idx >> 20;

    float4 osum = {0.f, 0.f, 0.f, 0.f};
    float4 dsum = {0.f, 0.f, 0.f, 0.f};
    #pragma unroll
    for (int p = 0; p < KSPLIT; ++p) {
        bf16x4 pp = *(const bf16x4*)(Opart + (((size_t)(p * BS + b)) * NI + c) * NPIX + n);
        float4 dd = *(const float4*)(dpart + ((size_t)(p * BS + b)) * NPIX + n);
        osum.x += (float)pp[0]; osum.y += (float)pp[1];
        osum.z += (float)pp[2]; osum.w += (float)pp[3];
        dsum.x += dd.x; dsum.y += dd.y; dsum.z += dd.z; dsum.w += dd.w;
    }

    size_t xb = ((size_t)(b * NI) + c) * NPIX + n;
    float4 xv = *(const float4*)(x + xb);
    float g = gamma[c];

    float4 r;
    r.x = g * (osum.x / dsum.x) + xv.x;
    r.y = g * (osum.y / dsum.y) + xv.y;
    r.z = g * (osum.z / dsum.z) + xv.z;
    r.w = g * (osum.w / dsum.w) + xv.w;
    *(float4*)(out + xb) = r;
}

extern "C" void kernel_launch(void* const* d_in, const int* in_sizes, int n_in,
                              void* d_out, int out_size, void* d_ws, size_t ws_size,
                              hipStream_t stream)
{
    const float* x     = (const float*)d_in[0];
    const float* wq    = (const float*)d_in[1];
    const float* bq    = (const float*)d_in[2];
    const float* wk    = (const float*)d_in[3];
    const float* bk    = (const float*)d_in[4];
    const float* wv    = (const float*)d_in[5];
    const float* bv    = (const float*)d_in[6];
    const float* gamma = (const float*)d_in[7];
    float* out = (float*)d_out;

    const size_t WPK = (size_t)10240 * 8;                      // 81920
    const size_t QPK = (size_t)BS * 128 * 2 * 2 * 2 * 32 * 8;  // 1,048,576
    const size_t KPK = (size_t)BS * 128 * 2 * 2 * 32 * 8;      // 524,288
    const size_t VPK = (size_t)BS * 128 * 2 * 2 * 256 * 8;     // 4,194,304
    __bf16* wpk   = (__bf16*)d_ws;
    __bf16* qpk   = wpk + WPK;
    __bf16* kpk   = qpk + QPK;
    __bf16* vpk   = kpk + KPK;
    __bf16* Opart = vpk + VPK;

    wconv_pack<<<dim3(40), 256, 0, stream>>>(wq, wk, wv, wpk);
    qkv_mfma<<<dim3(NPIX / 32, BS), 256, 0, stream>>>(x, wpk, bq, bk, bv, qpk, kpk, vpk);

    // KSPLIT=4 needs ~45.5 MB of workspace; fall back to 2-way if short.
    const size_t OSZ4  = (size_t)4 * BS * NI * NPIX;
    const size_t need4 = (WPK + QPK + KPK + VPK + OSZ4) * sizeof(__bf16)
                       + (size_t)4 * BS * NPIX * sizeof(float);
    if (ws_size >= need4) {
        float* dpart = (float*)(Opart + OSZ4);
        attn_mfma<4><<<dim3(64, 4, BS), 256, 0, stream>>>(qpk, kpk, vpk, Opart, dpart);
        combine<4><<<dim3(BS * NI * NPIX / 1024), 256, 0, stream>>>(x, gamma, Opart, dpart, out);
    } else {
        const size_t OSZ2 = (size_t)2 * BS * NI * NPIX;
        float* dpart = (float*)(Opart + OSZ2);
        attn_mfma<2><<<dim3(64, 2, BS), 256, 0, stream>>>(qpk, kpk, vpk, Opart, dpart);
        combine<2><<<dim3(BS * NI * NPIX / 1024), 256, 0, stream>>>(x, gamma, Opart, dpart, out);
    }
}